// Round 2
// baseline (657.005 us; speedup 1.0000x reference)
//
#include <hip/hip_runtime.h>
#include <hip/hip_bf16.h>
#include <cstdint>
#include <cstddef>

#define B_ 8
#define T_ 4096
#define D_ 1024
#define H_ 1024
#define M_ (B_*T_)
#define NCHUNK 64
#define CLEN 64

using bf16x8   = __attribute__((ext_vector_type(8))) __bf16;
using floatx4  = __attribute__((ext_vector_type(4))) float;
using float4v  = __attribute__((ext_vector_type(4))) float;
using ushort4v = __attribute__((ext_vector_type(4))) unsigned short;
using aw2_t    = __attribute__((ext_vector_type(2))) _Float16;  // packed (a, w)
using halfx8   = __attribute__((ext_vector_type(8))) _Float16;  // 4 aw2 pairs

__device__ inline unsigned short f2bf(float f) {
  union { float f; unsigned u; } v; v.f = f;
  unsigned u = v.u;
  u += 0x7fffu + ((u >> 16) & 1u);   // round-to-nearest-even
  return (unsigned short)(u >> 16);
}

__device__ inline void async_load16(const void* g, void* l) {
  __builtin_amdgcn_global_load_lds((const __attribute__((address_space(1))) void*)g,
                                   (__attribute__((address_space(3))) void*)l,
                                   16, 0, 0);
}

// ---------- fused prep: cast x (fp32->bf16) + transpose/cast W ----------
// blocks [0,16384): cast 8 floats/thread; blocks [16384,18432): 32x32 W transpose
__global__ __launch_bounds__(256) void prep_kernel(const float* __restrict__ x,
                                                   unsigned short* __restrict__ xb,
                                                   const float* __restrict__ Wz,
                                                   const float* __restrict__ Wh,
                                                   unsigned short* __restrict__ Wzt,
                                                   unsigned short* __restrict__ Wht) {
  __shared__ float tile[32][33];
  const int bid = blockIdx.x;
  if (bid < 16384) {
    size_t i = ((size_t)bid * 256 + threadIdx.x) * 2;  // 2 groups of 4
#pragma unroll
    for (int j = 0; j < 2; ++j) {
      float4v v = ((const float4v*)x)[i + j];
      ushort4v o = { f2bf(v[0]), f2bf(v[1]), f2bf(v[2]), f2bf(v[3]) };
      ((ushort4v*)xb)[i + j] = o;
    }
  } else {
    const int b2 = bid - 16384;            // 0..2047
    const int z = b2 >> 10;                // 0..1 (Wz / Wh)
    const int rem = b2 & 1023;
    const int bx = rem & 31, by = rem >> 5;
    const int tx = threadIdx.x & 31, ty = threadIdx.x >> 5;
    const float* W = z ? Wh : Wz;
    unsigned short* Wt = z ? Wht : Wzt;
    const int n0 = bx * 32, k0 = by * 32;
#pragma unroll
    for (int j = 0; j < 4; ++j) {
      int kr = ty + j * 8;
      tile[kr][tx] = W[(size_t)(k0 + kr) * H_ + n0 + tx];
    }
    __syncthreads();
#pragma unroll
    for (int j = 0; j < 4; ++j) {
      int nr = ty + j * 8;
      Wt[(size_t)(n0 + nr) * D_ + k0 + tx] = f2bf(tile[tx][nr]);
    }
  }
}

// ------------- dual-output MFMA GEMM + activation epilogue -------------
// (round-0 proven version: 128x128 dual tile, BK=64, XOR-swizzled LDS,
//  global_load_lds staging, 3 blocks/CU, 183.6 us measured)
__global__ __launch_bounds__(256, 2) void gemm_kernel(
    const unsigned short* __restrict__ xb,    // [M_][D_] bf16
    const unsigned short* __restrict__ wzt,   // [H_][D_] bf16 (transposed)
    const unsigned short* __restrict__ wht,   // [H_][D_] bf16
    const float* __restrict__ bz, const float* __restrict__ bh,
    aw2_t* __restrict__ aw_out) {
  __shared__ __align__(16) unsigned short ldsA[128 * 64];
  __shared__ __align__(16) unsigned short ldsBz[128 * 64];
  __shared__ __align__(16) unsigned short ldsBh[128 * 64];

  const int tid = threadIdx.x;
  const int lane = tid & 63, wid = tid >> 6;
  const int wm = wid >> 1, wn = wid & 1;
  const int row16 = lane & 15, quad = lane >> 4;

  // XCD-aware swizzle: 8 n-tiles of one m-strip consecutive on one XCD.
  int g = blockIdx.x;
  int x = g & 7, j = g >> 3;           // j in 0..255
  int n_idx = j & 7;
  int m_idx = (x << 5) | (j >> 3);
  const int m0 = m_idx * 128, n0 = n_idx * 128;

  floatx4 accz[4][4], acch[4][4];
#pragma unroll
  for (int mi = 0; mi < 4; ++mi)
#pragma unroll
    for (int ni = 0; ni < 4; ++ni) {
      accz[mi][ni] = (floatx4){0.f, 0.f, 0.f, 0.f};
      acch[mi][ni] = (floatx4){0.f, 0.f, 0.f, 0.f};
    }

  // staging: seg s = tid + 256*t (t=0..3): row = s>>3 = (tid>>3)+32t,
  // stored slot p = s&7 = tid&7, logical k-block j = (p - row)&7 =
  // ((tid&7) - (tid>>3))&7  (32t == 0 mod 8) -> t-independent.
  const int srow = tid >> 3;
  const int jblk = ((tid & 7) - srow) & 7;
  const unsigned short* aSrc  = xb  + (size_t)(m0 + srow) * D_ + jblk * 8;
  const unsigned short* zSrc  = wzt + (size_t)(n0 + srow) * D_ + jblk * 8;
  const unsigned short* hSrc  = wht + (size_t)(n0 + srow) * D_ + jblk * 8;

  // frag-read slot: p(kh) = (kh*4 + quad + row16) & 7  (row%8 == row16%8)
  const int p0 = (quad + row16) & 7;
  const int p1 = p0 ^ 4;

  for (int kk = 0; kk < D_; kk += 64) {
#pragma unroll
    for (int t = 0; t < 4; ++t) {
      size_t roff = (size_t)(32 * t) * D_ + kk;
      int doff = (tid + 256 * t) * 8;
      async_load16(aSrc + roff, &ldsA[doff]);
      async_load16(zSrc + roff, &ldsBz[doff]);
      async_load16(hSrc + roff, &ldsBh[doff]);
    }
    __syncthreads();

#pragma unroll
    for (int kh = 0; kh < 2; ++kh) {
      const int p = kh ? p1 : p0;
      bf16x8 af[4], bzf[4], bhf[4];
#pragma unroll
      for (int mi = 0; mi < 4; ++mi)
        af[mi] = *(const bf16x8*)&ldsA[(wm * 64 + mi * 16 + row16) * 64 + p * 8];
#pragma unroll
      for (int ni = 0; ni < 4; ++ni) {
        bzf[ni] = *(const bf16x8*)&ldsBz[(wn * 64 + ni * 16 + row16) * 64 + p * 8];
        bhf[ni] = *(const bf16x8*)&ldsBh[(wn * 64 + ni * 16 + row16) * 64 + p * 8];
      }
#pragma unroll
      for (int mi = 0; mi < 4; ++mi)
#pragma unroll
        for (int ni = 0; ni < 4; ++ni) {
          accz[mi][ni] = __builtin_amdgcn_mfma_f32_16x16x32_bf16(af[mi], bzf[ni], accz[mi][ni], 0, 0, 0);
          acch[mi][ni] = __builtin_amdgcn_mfma_f32_16x16x32_bf16(af[mi], bhf[ni], acch[mi][ni], 0, 0, 0);
        }
    }
    __syncthreads();
  }

  // epilogue: C/D layout col=lane&15, row=quad*4+reg
#pragma unroll
  for (int mi = 0; mi < 4; ++mi) {
#pragma unroll
    for (int ni = 0; ni < 4; ++ni) {
      int col = n0 + wn * 64 + ni * 16 + row16;
      float bzv = bz[col], bhv = bh[col];
#pragma unroll
      for (int r = 0; r < 4; ++r) {
        int row = m0 + wm * 64 + mi * 16 + quad * 4 + r;
        float k   = accz[mi][ni][r] + bzv;
        float pre = acch[mi][ni][r] + bhv;
        float z  = 1.f / (1.f + __expf(-k));   // sigmoid(k)
        float av = 1.f / (1.f + __expf(k));    // sigmoid(-k) = 1-z
        float gg = (pre >= 0.f) ? (pre + 0.5f) : 1.f / (1.f + __expf(-pre));
        aw2_t o = { (_Float16)av, (_Float16)(z * gg) };
        aw_out[(size_t)row * H_ + col] = o;
      }
    }
  }
}

// ------------- single-pass scan with decoupled lookback -------------
// 512 blocks = (b, c); each block: (A) local chunk scan -> publish (P,S) with
// release flag=1; (B) lookback across predecessors (locals or inclusives) to
// get carry Hin; publish inclusive flag=2; (C) replay chunk (aw re-read hits
// L3) writing out. All 512 small blocks are co-resident (no LDS, low VGPR),
// so spin-waiting cannot deadlock regardless of dispatch order.
__global__ __launch_bounds__(256) void scan_fused(const halfx8* __restrict__ aw,
                                                  const float* __restrict__ h0,
                                                  float4v* __restrict__ PL,
                                                  float4v* __restrict__ SL,
                                                  float4v* __restrict__ SI,
                                                  int* __restrict__ flags,
                                                  float* __restrict__ out) {
  const int c = blockIdx.x & (NCHUNK - 1);
  const int b = blockIdx.x >> 6;
  const int h4 = threadIdx.x;   // h = h4*4
  const size_t base = (size_t)(b * T_ + c * CLEN) * (H_ / 4) + h4;

  // ---- phase A: local scan (P = prod a, S = local affine term) ----
  float p0 = 1.f, p1 = 1.f, p2 = 1.f, p3 = 1.f;
  float s0 = 0.f, s1 = 0.f, s2 = 0.f, s3 = 0.f;
#pragma unroll 8
  for (int i = 0; i < CLEN; ++i) {
    halfx8 v = aw[base + (size_t)i * (H_ / 4)];
    float a0 = (float)v[0], w0 = (float)v[1];
    float a1 = (float)v[2], w1 = (float)v[3];
    float a2 = (float)v[4], w2 = (float)v[5];
    float a3 = (float)v[6], w3 = (float)v[7];
    s0 = a0 * s0 + w0; p0 *= a0;
    s1 = a1 * s1 + w1; p1 *= a1;
    s2 = a2 * s2 + w2; p2 *= a2;
    s3 = a3 * s3 + w3; p3 *= a3;
  }
  const size_t pidx = (size_t)(b * NCHUNK + c) * 256 + h4;
  PL[pidx] = (float4v){p0, p1, p2, p3};
  SL[pidx] = (float4v){s0, s1, s2, s3};
  __threadfence();
  __syncthreads();
  if (threadIdx.x == 0)
    __hip_atomic_store(&flags[b * NCHUNK + c], 1, __ATOMIC_RELEASE, __HIP_MEMORY_SCOPE_AGENT);

  // ---- phase B: lookback (compose right-to-left over predecessors) ----
  __shared__ int sflag;
  float4v Pr = (float4v){1.f, 1.f, 1.f, 1.f};
  float4v Sr = (float4v){0.f, 0.f, 0.f, 0.f};
  float4v Hin;
  int idx = c - 1;
  for (;;) {
    if (idx < 0) {
      const float4v hv = *(const float4v*)&h0[(size_t)b * H_ + h4 * 4];
      float4v g;
#pragma unroll
      for (int j = 0; j < 4; ++j)
        g[j] = (hv[j] >= 0.f) ? (hv[j] + 0.5f) : 1.f / (1.f + __expf(-hv[j]));
      Hin = Pr * g + Sr;
      break;
    }
    if (threadIdx.x == 0) {
      int f = __hip_atomic_load(&flags[b * NCHUNK + idx], __ATOMIC_ACQUIRE, __HIP_MEMORY_SCOPE_AGENT);
      while (f == 0) {
        __builtin_amdgcn_s_sleep(2);
        f = __hip_atomic_load(&flags[b * NCHUNK + idx], __ATOMIC_ACQUIRE, __HIP_MEMORY_SCOPE_AGENT);
      }
      sflag = f;
    }
    __syncthreads();
    const int f = sflag;
    __syncthreads();   // protect sflag before next-iteration rewrite
    const size_t q = (size_t)(b * NCHUNK + idx) * 256 + h4;
    if (f == 2) { Hin = Pr * SI[q] + Sr; break; }
    Sr = Pr * SL[q] + Sr;
    Pr = Pr * PL[q];
    --idx;
  }

  // inclusive publish: V = P_local * Hin + S_local
  SI[pidx] = (float4v){p0 * Hin[0] + s0, p1 * Hin[1] + s1, p2 * Hin[2] + s2, p3 * Hin[3] + s3};
  __threadfence();
  __syncthreads();
  if (threadIdx.x == 0)
    __hip_atomic_store(&flags[b * NCHUNK + c], 2, __ATOMIC_RELEASE, __HIP_MEMORY_SCOPE_AGENT);

  float4v* outv = (float4v*)out;
  if (c == 0) {   // out[:,0,:] = g(h0)
    const float4v hv = *(const float4v*)&h0[(size_t)b * H_ + h4 * 4];
    float4v g;
#pragma unroll
    for (int j = 0; j < 4; ++j)
      g[j] = (hv[j] >= 0.f) ? (hv[j] + 0.5f) : 1.f / (1.f + __expf(-hv[j]));
    outv[(size_t)b * (T_ + 1) * (H_ / 4) + h4] = g;
  }

  // ---- phase C: replay chunk with carry (aw re-read: L3-resident) ----
  float c0 = Hin[0], c1 = Hin[1], c2 = Hin[2], c3 = Hin[3];
  const size_t obase = ((size_t)b * (T_ + 1) + c * CLEN + 1) * (H_ / 4) + h4;
#pragma unroll 8
  for (int i = 0; i < CLEN; ++i) {
    halfx8 v = aw[base + (size_t)i * (H_ / 4)];
    c0 = (float)v[0] * c0 + (float)v[1];
    c1 = (float)v[2] * c1 + (float)v[3];
    c2 = (float)v[4] * c2 + (float)v[5];
    c3 = (float)v[6] * c3 + (float)v[7];
    outv[obase + (size_t)i * (H_ / 4)] = (float4v){c0, c1, c2, c3};
  }
}

extern "C" void kernel_launch(void* const* d_in, const int* in_sizes, int n_in,
                              void* d_out, int out_size, void* d_ws, size_t ws_size,
                              hipStream_t stream) {
  const float* x  = (const float*)d_in[0];
  const float* h0 = (const float*)d_in[1];
  const float* Wz = (const float*)d_in[2];
  const float* bz = (const float*)d_in[3];
  const float* Wh = (const float*)d_in[4];
  const float* bh = (const float*)d_in[5];
  float* out = (float*)d_out;

  char* ws = (char*)d_ws;
  // layout: xb 64MB | wzt 2MB | wht 2MB | aw 128MB | PL 2MB | SL 2MB | SI 2MB
  // flags (2KB) live in the tail of xb: xb is fully consumed by gemm before
  // the scan runs; flags are memset between gemm and scan (stream-ordered),
  // and prep rewrites those bytes on every graph replay before gemm reads them.
  unsigned short* xb  = (unsigned short*)(ws);
  unsigned short* wzt = (unsigned short*)(ws + 67108864ULL);
  unsigned short* wht = (unsigned short*)(ws + 69206016ULL);
  aw2_t* aw_ws = (aw2_t*)(ws + 71303168ULL);
  float4v* PL_ws = (float4v*)(ws + 71303168ULL + 134217728ULL);
  float4v* SL_ws = (float4v*)(ws + 71303168ULL + 134217728ULL + 2097152ULL);
  float4v* SI_ws = (float4v*)(ws + 71303168ULL + 134217728ULL + 2ULL * 2097152ULL);
  int* flags = (int*)(ws + 67108864ULL - 2048ULL);

  hipLaunchKernelGGL(prep_kernel, dim3(16384 + 2048), dim3(256), 0, stream,
                     x, xb, Wz, Wh, wzt, wht);
  hipLaunchKernelGGL(gemm_kernel, dim3(2048), dim3(256), 0, stream,
                     xb, wzt, wht, bz, bh, aw_ws);
  hipMemsetAsync(flags, 0, (size_t)(B_ * NCHUNK) * sizeof(int), stream);
  hipLaunchKernelGGL(scan_fused, dim3(B_ * NCHUNK), dim3(256), 0, stream,
                     (const halfx8*)aw_ws, h0, PL_ws, SL_ws, SI_ws, flags, out);
}

// Round 3
// 462.611 us; speedup vs baseline: 1.4202x; 1.4202x over previous
//
#include <hip/hip_runtime.h>
#include <hip/hip_bf16.h>
#include <cstdint>
#include <cstddef>

#define B_ 8
#define T_ 4096
#define D_ 1024
#define H_ 1024
#define M_ (B_*T_)
#define NCHUNK 64
#define CLEN 64

using bf16x8   = __attribute__((ext_vector_type(8))) __bf16;
using floatx4  = __attribute__((ext_vector_type(4))) float;
using float4v  = __attribute__((ext_vector_type(4))) float;
using float2v  = __attribute__((ext_vector_type(2))) float;
using ushort4v = __attribute__((ext_vector_type(4))) unsigned short;
using aw2_t    = __attribute__((ext_vector_type(2))) _Float16;  // packed (a, w)
using halfx4   = __attribute__((ext_vector_type(4))) _Float16;  // 2 aw pairs
using halfx8   = __attribute__((ext_vector_type(8))) _Float16;  // 4 aw pairs

__device__ inline unsigned short f2bf(float f) {
  union { float f; unsigned u; } v; v.f = f;
  unsigned u = v.u;
  u += 0x7fffu + ((u >> 16) & 1u);   // round-to-nearest-even
  return (unsigned short)(u >> 16);
}

__device__ inline void async_load16(const void* g, void* l) {
  __builtin_amdgcn_global_load_lds((const __attribute__((address_space(1))) void*)g,
                                   (__attribute__((address_space(3))) void*)l,
                                   16, 0, 0);
}

// ---------- fused prep: cast x (fp32->bf16) + transpose/cast W ----------
// blocks [0,16384): cast 8 floats/thread; blocks [16384,18432): 32x32 W transpose
__global__ __launch_bounds__(256) void prep_kernel(const float* __restrict__ x,
                                                   unsigned short* __restrict__ xb,
                                                   const float* __restrict__ Wz,
                                                   const float* __restrict__ Wh,
                                                   unsigned short* __restrict__ Wzt,
                                                   unsigned short* __restrict__ Wht) {
  __shared__ float tile[32][33];
  const int bid = blockIdx.x;
  if (bid < 16384) {
    size_t i = ((size_t)bid * 256 + threadIdx.x) * 2;  // 2 groups of 4
#pragma unroll
    for (int j = 0; j < 2; ++j) {
      float4v v = ((const float4v*)x)[i + j];
      ushort4v o = { f2bf(v[0]), f2bf(v[1]), f2bf(v[2]), f2bf(v[3]) };
      ((ushort4v*)xb)[i + j] = o;
    }
  } else {
    const int b2 = bid - 16384;            // 0..2047
    const int z = b2 >> 10;                // 0..1 (Wz / Wh)
    const int rem = b2 & 1023;
    const int bx = rem & 31, by = rem >> 5;
    const int tx = threadIdx.x & 31, ty = threadIdx.x >> 5;
    const float* W = z ? Wh : Wz;
    unsigned short* Wt = z ? Wht : Wzt;
    const int n0 = bx * 32, k0 = by * 32;
#pragma unroll
    for (int j = 0; j < 4; ++j) {
      int kr = ty + j * 8;
      tile[kr][tx] = W[(size_t)(k0 + kr) * H_ + n0 + tx];
    }
    __syncthreads();
#pragma unroll
    for (int j = 0; j < 4; ++j) {
      int nr = ty + j * 8;
      Wt[(size_t)(n0 + nr) * D_ + k0 + tx] = f2bf(tile[tx][nr]);
    }
  }
}

// ------------- dual-output MFMA GEMM + activation epilogue + fused chunk summary -------------
// Main loop = round-0 proven version (128x128 dual tile, BK=64, XOR-swizzled
// LDS, global_load_lds staging, 183.6 us measured). Epilogue additionally
// computes the per-chunk scan summaries (P = prod a, S = affine term) that
// scan_pass1 used to produce from a full 128 MB re-read of aw:
//   - a 64-row chunk for one col lives in one wave (rows = mi*16+quad*4+r)
//   - fold r in-lane (rows ascending), butterfly-compose across quads via
//     shfl_xor(16/32) with order-aware select, compose mi blocks in-lane
//   - fold uses the fp16-ROUNDED (a,w) so carries match pass3's replay exactly
__global__ __launch_bounds__(256, 2) void gemm_kernel(
    const unsigned short* __restrict__ xb,    // [M_][D_] bf16
    const unsigned short* __restrict__ wzt,   // [H_][D_] bf16 (transposed)
    const unsigned short* __restrict__ wht,   // [H_][D_] bf16
    const float* __restrict__ bz, const float* __restrict__ bh,
    aw2_t* __restrict__ aw_out,
    float* __restrict__ P_ws, float* __restrict__ S_ws) {
  __shared__ __align__(16) unsigned short ldsA[128 * 64];
  __shared__ __align__(16) unsigned short ldsBz[128 * 64];
  __shared__ __align__(16) unsigned short ldsBh[128 * 64];

  const int tid = threadIdx.x;
  const int lane = tid & 63, wid = tid >> 6;
  const int wm = wid >> 1, wn = wid & 1;
  const int row16 = lane & 15, quad = lane >> 4;

  // XCD-aware swizzle: 8 n-tiles of one m-strip consecutive on one XCD.
  int g = blockIdx.x;
  int x = g & 7, j = g >> 3;           // j in 0..255
  int n_idx = j & 7;
  int m_idx = (x << 5) | (j >> 3);
  const int m0 = m_idx * 128, n0 = n_idx * 128;

  floatx4 accz[4][4], acch[4][4];
#pragma unroll
  for (int mi = 0; mi < 4; ++mi)
#pragma unroll
    for (int ni = 0; ni < 4; ++ni) {
      accz[mi][ni] = (floatx4){0.f, 0.f, 0.f, 0.f};
      acch[mi][ni] = (floatx4){0.f, 0.f, 0.f, 0.f};
    }

  // staging: seg s = tid + 256*t (t=0..3): row = s>>3 = (tid>>3)+32t,
  // stored slot p = s&7 = tid&7, logical k-block j = (p - row)&7 =
  // ((tid&7) - (tid>>3))&7  (32t == 0 mod 8) -> t-independent.
  const int srow = tid >> 3;
  const int jblk = ((tid & 7) - srow) & 7;
  const unsigned short* aSrc  = xb  + (size_t)(m0 + srow) * D_ + jblk * 8;
  const unsigned short* zSrc  = wzt + (size_t)(n0 + srow) * D_ + jblk * 8;
  const unsigned short* hSrc  = wht + (size_t)(n0 + srow) * D_ + jblk * 8;

  // frag-read slot: p(kh) = (kh*4 + quad + row16) & 7  (row%8 == row16%8)
  const int p0 = (quad + row16) & 7;
  const int p1 = p0 ^ 4;

  for (int kk = 0; kk < D_; kk += 64) {
#pragma unroll
    for (int t = 0; t < 4; ++t) {
      size_t roff = (size_t)(32 * t) * D_ + kk;
      int doff = (tid + 256 * t) * 8;
      async_load16(aSrc + roff, &ldsA[doff]);
      async_load16(zSrc + roff, &ldsBz[doff]);
      async_load16(hSrc + roff, &ldsBh[doff]);
    }
    __syncthreads();

#pragma unroll
    for (int kh = 0; kh < 2; ++kh) {
      const int p = kh ? p1 : p0;
      bf16x8 af[4], bzf[4], bhf[4];
#pragma unroll
      for (int mi = 0; mi < 4; ++mi)
        af[mi] = *(const bf16x8*)&ldsA[(wm * 64 + mi * 16 + row16) * 64 + p * 8];
#pragma unroll
      for (int ni = 0; ni < 4; ++ni) {
        bzf[ni] = *(const bf16x8*)&ldsBz[(wn * 64 + ni * 16 + row16) * 64 + p * 8];
        bhf[ni] = *(const bf16x8*)&ldsBh[(wn * 64 + ni * 16 + row16) * 64 + p * 8];
      }
#pragma unroll
      for (int mi = 0; mi < 4; ++mi)
#pragma unroll
        for (int ni = 0; ni < 4; ++ni) {
          accz[mi][ni] = __builtin_amdgcn_mfma_f32_16x16x32_bf16(af[mi], bzf[ni], accz[mi][ni], 0, 0, 0);
          acch[mi][ni] = __builtin_amdgcn_mfma_f32_16x16x32_bf16(af[mi], bhf[ni], acch[mi][ni], 0, 0, 0);
        }
    }
    __syncthreads();
  }

  // epilogue: C/D layout col=lane&15, row=quad*4+reg
  const int b_of = m0 >> 12;                       // batch of this tile
  const int cidx = ((m0 & (T_ - 1)) >> 6) + wm;    // global chunk id (64-row)
#pragma unroll
  for (int ni = 0; ni < 4; ++ni) {
    const int col = n0 + wn * 64 + ni * 16 + row16;
    const float bzv = bz[col], bhv = bh[col];
    float Pc = 1.f, Sc = 0.f;                      // running chunk affine map
#pragma unroll
    for (int mi = 0; mi < 4; ++mi) {
      float pm = 1.f, sm = 0.f;                    // per-lane 4-row segment
#pragma unroll
      for (int r = 0; r < 4; ++r) {
        const int row = m0 + wm * 64 + mi * 16 + quad * 4 + r;
        float k   = accz[mi][ni][r] + bzv;
        float pre = acch[mi][ni][r] + bhv;
        float z  = 1.f / (1.f + __expf(-k));   // sigmoid(k)
        float av = 1.f / (1.f + __expf(k));    // sigmoid(-k) = 1-z
        float gg = (pre >= 0.f) ? (pre + 0.5f) : 1.f / (1.f + __expf(-pre));
        _Float16 ah = (_Float16)av, wh = (_Float16)(z * gg);
        aw2_t o = { ah, wh };
        aw_out[(size_t)row * H_ + col] = o;
        // fold rows ascending with the fp16-rounded values (match pass3)
        float afv = (float)ah, wfv = (float)wh;
        sm = afv * sm + wfv;
        pm = afv * pm;
      }
      // butterfly-compose the 4 quad segments (rows ascending with quad)
      float pp = __shfl_xor(pm, 16), sp = __shfl_xor(sm, 16);
      sm = (quad & 1) ? (pm * sp + sm) : (pp * sm + sp);
      pm = pm * pp;
      pp = __shfl_xor(pm, 32); sp = __shfl_xor(sm, 32);
      sm = (quad & 2) ? (pm * sp + sm) : (pp * sm + sp);
      pm = pm * pp;
      // compose this 16-row block onto the running chunk map (mi ascending)
      Sc = pm * Sc + sm;
      Pc = pm * Pc;
    }
    if (quad == 0) {
      size_t o = ((size_t)b_of * H_ + col) * NCHUNK + cidx;
      P_ws[o] = Pc; S_ws[o] = Sc;
    }
  }
}

// ------------- scan pass 2: chunk-level carries + out[:,0,:] -------------
__global__ __launch_bounds__(256) void scan_pass2(const float* __restrict__ h0,
                                                  const float* __restrict__ P,
                                                  const float* __restrict__ S,
                                                  float* __restrict__ carry,
                                                  float* __restrict__ out) {
  int gid = blockIdx.x * 256 + threadIdx.x;  // 0..8191
  int b = gid >> 10, h = gid & 1023;
  float v = h0[(size_t)b * H_ + h];
  float cur = (v >= 0.f) ? (v + 0.5f) : 1.f / (1.f + __expf(-v));  // g(h0)
  out[((size_t)b * (T_ + 1)) * H_ + h] = cur;
  const float4v* Pv = (const float4v*)&P[((size_t)b * H_ + h) * NCHUNK];
  const float4v* Sv = (const float4v*)&S[((size_t)b * H_ + h) * NCHUNK];
  float4v* Cv = (float4v*)&carry[((size_t)b * H_ + h) * NCHUNK];
#pragma unroll
  for (int j = 0; j < NCHUNK / 4; ++j) {
    float4v p = Pv[j], s = Sv[j], cc;
    cc[0] = cur; cur = p[0] * cur + s[0];
    cc[1] = cur; cur = p[1] * cur + s[1];
    cc[2] = cur; cur = p[2] * cur + s[2];
    cc[3] = cur; cur = p[3] * cur + s[3];
    Cv[j] = cc;
  }
}

// ------------- scan pass 3: replay chunks with carries (2 h per thread) -------------
// 512 threads/block, (NCHUNK, B_) grid -> 4096 waves = 16 waves/CU for
// latency hiding (was 8). aw read follows the gemm write closely -> L3 hits.
__global__ __launch_bounds__(512) void scan_pass3(const halfx4* __restrict__ aw,
                                                  const float* __restrict__ carry,
                                                  float* __restrict__ out) {
  int c = blockIdx.x;
  int b = blockIdx.y;
  int h2 = threadIdx.x;   // h = h2*2
  size_t base = (size_t)(b * T_ + c * CLEN) * (H_ / 2) + h2;
  size_t cb = ((size_t)b * H_ + h2 * 2) * NCHUNK + c;
  float c0 = carry[cb], c1 = carry[cb + NCHUNK];
  size_t obase = ((size_t)b * (T_ + 1) + c * CLEN + 1) * (H_ / 2) + h2;
  float2v* outv = (float2v*)out;
#pragma unroll 8
  for (int i = 0; i < CLEN; ++i) {
    halfx4 v = aw[base + (size_t)i * (H_ / 2)];
    c0 = (float)v[0] * c0 + (float)v[1];
    c1 = (float)v[2] * c1 + (float)v[3];
    outv[obase + (size_t)i * (H_ / 2)] = (float2v){c0, c1};
  }
}

extern "C" void kernel_launch(void* const* d_in, const int* in_sizes, int n_in,
                              void* d_out, int out_size, void* d_ws, size_t ws_size,
                              hipStream_t stream) {
  const float* x  = (const float*)d_in[0];
  const float* h0 = (const float*)d_in[1];
  const float* Wz = (const float*)d_in[2];
  const float* bz = (const float*)d_in[3];
  const float* Wh = (const float*)d_in[4];
  const float* bh = (const float*)d_in[5];
  float* out = (float*)d_out;

  char* ws = (char*)d_ws;
  // layout: xb 64MB | wzt 2MB | wht 2MB | aw 128MB | P 2MB | S 2MB | carry 2MB
  unsigned short* xb  = (unsigned short*)(ws);
  unsigned short* wzt = (unsigned short*)(ws + 67108864ULL);
  unsigned short* wht = (unsigned short*)(ws + 69206016ULL);
  aw2_t* aw_ws = (aw2_t*)(ws + 71303168ULL);
  float* P_ws  = (float*)(ws + 71303168ULL + 134217728ULL);
  float* S_ws  = (float*)(ws + 71303168ULL + 134217728ULL + 2097152ULL);
  float* c_ws  = (float*)(ws + 71303168ULL + 134217728ULL + 2ULL * 2097152ULL);

  hipLaunchKernelGGL(prep_kernel, dim3(16384 + 2048), dim3(256), 0, stream,
                     x, xb, Wz, Wh, wzt, wht);
  hipLaunchKernelGGL(gemm_kernel, dim3(2048), dim3(256), 0, stream,
                     xb, wzt, wht, bz, bh, aw_ws, P_ws, S_ws);
  hipLaunchKernelGGL(scan_pass2, dim3(32), dim3(256), 0, stream, h0, P_ws, S_ws, c_ws, out);
  hipLaunchKernelGGL(scan_pass3, dim3(NCHUNK, B_), dim3(512), 0, stream,
                     (const halfx4*)aw_ws, c_ws, out);
}